// Round 6
// baseline (74.960 us; speedup 1.0000x reference)
//
#include <hip/hip_runtime.h>

// PolynomialRegression, single fused kernel (no workspace):
//   y[b][o] = bias_o + sum_i x[b][i] * ( (U_o x[b])_i + W1[o][i] )
// BM=32 row tiles (grid 128x10 = 1280 blocks, ~5/CU) to hide latency.
// U_o rows read directly from W (fp32, L2-hot) as MFMA B-frags with
// in-register half-up bf16 pack; j<i masking only on diagonal frags.
// Balanced triangle: wave w owns i-groups {32w,+32} u {224-32w,+32}
// -> every wave does exactly 36 MFMA. Epilogue x comes from LDS (bf16).

#define DD 256
#define NF 33153
#define TPB 256
#define BM 32
#define ASTRIDE 264   // bf16 elems; row stride 528 B -> 2-way LDS alias (free)

typedef __attribute__((ext_vector_type(8))) short short8;
typedef __attribute__((ext_vector_type(4))) float floatx4;
typedef __attribute__((ext_vector_type(4), aligned(4))) float float4a;  // 4B-aligned

union S8U { unsigned u[4]; short8 s; };

__device__ inline unsigned pack2(float lo, float hi) {   // 2xfp32 -> bf16x2, half-up
    unsigned a = __builtin_bit_cast(unsigned, hi) + 0x8000u;
    unsigned b = __builtin_bit_cast(unsigned, lo) + 0x8000u;
    return __builtin_amdgcn_perm(a, b, 0x07060302u);     // [a.hi16 | b.hi16]
}

__global__ __launch_bounds__(TPB, 4)
void PolynomialRegression_75385265979710_kernel(const float* __restrict__ x,
                                                const float* __restrict__ W,
                                                float* __restrict__ out) {
    __shared__ __align__(16) unsigned short As[BM * ASTRIDE];  // 16896 B
    __shared__ float red[4 * BM];

    const int tid  = threadIdx.x;
    const int lane = tid & 63, wave = tid >> 6;
    const int ln   = lane & 15, quad = lane >> 4;
    const int q8   = quad * 8;
    const int rowbase = blockIdx.x * BM;
    const int o  = blockIdx.y;
    const int g1 = wave, g2 = 7 - wave;

    // --- stage x-tile (32 rows x 256) fp32 -> bf16 into LDS ---
#pragma unroll
    for (int it = 0; it < 4; ++it) {
        int idx = it * 2048 + tid * 8;
        int r = idx >> 8, c = idx & 255;
        const float* src = &x[(rowbase + r) * DD + c];
        float4a v0 = *(const float4a*)src;
        float4a v1 = *(const float4a*)(src + 4);
        S8U p;
        p.u[0] = pack2(v0.x, v0.y); p.u[1] = pack2(v0.z, v0.w);
        p.u[2] = pack2(v1.x, v1.y); p.u[3] = pack2(v1.z, v1.w);
        *(short8*)&As[r * ASTRIDE + c] = p.s;
    }
    __syncthreads();

    // tiles: nt 0,1 -> i in [32*g1, +32); nt 2,3 -> i in [32*g2, +32)
    int iRow[4], bBase[4];
#pragma unroll
    for (int nt = 0; nt < 4; ++nt) {
        int g = (nt < 2) ? g1 : g2;
        int i = g * 32 + (nt & 1) * 16 + ln;
        iRow[nt]  = i;
        bBase[nt] = o * NF + 257 + i * 255 - ((i * (i - 1)) >> 1);  // + j, j>=i valid
    }

    floatx4 acc[2][4];
#pragma unroll
    for (int mt = 0; mt < 2; ++mt)
#pragma unroll
        for (int nt = 0; nt < 4; ++nt) acc[mt][nt] = (floatx4)0.f;

    auto loadA = [&](int kk, short8* a) {
#pragma unroll
        for (int mt = 0; mt < 2; ++mt)
            a[mt] = *(const short8*)&As[(mt * 16 + ln) * ASTRIDE + kk + q8];
    };
    auto loadB = [&](int nt, int kk) -> short8 {
        const float* p = &W[bBase[nt] + kk + q8];
        float4a w0 = *(const float4a*)p;
        float4a w1 = *(const float4a*)(p + 4);
        S8U r;
        r.u[0] = pack2(w0.x, w0.y); r.u[1] = pack2(w0.z, w0.w);
        r.u[2] = pack2(w1.x, w1.y); r.u[3] = pack2(w1.z, w1.w);
        return r.s;
    };
    auto loadBmask = [&](int nt, int kk) -> short8 {   // zero j<i (diagonal chunk)
        int di = iRow[nt] - kk;
        const float* p = &W[bBase[nt] + kk + q8];
        float4a w0 = *(const float4a*)p;
        float4a w1 = *(const float4a*)(p + 4);
        float f[8] = {w0.x, w0.y, w0.z, w0.w, w1.x, w1.y, w1.z, w1.w};
#pragma unroll
        for (int e = 0; e < 8; ++e)
            if (q8 + e < di) f[e] = 0.f;
        S8U r;
        r.u[0] = pack2(f[0], f[1]); r.u[1] = pack2(f[2], f[3]);
        r.u[2] = pack2(f[4], f[5]); r.u[3] = pack2(f[6], f[7]);
        return r.s;
    };
    auto mfma2 = [&](short8* a, short8 b0, short8 b1, int nlo) {
#pragma unroll
        for (int mt = 0; mt < 2; ++mt) {
            acc[mt][nlo]     = __builtin_amdgcn_mfma_f32_16x16x32_bf16(a[mt], b0, acc[mt][nlo],     0, 0, 0);
            acc[mt][nlo + 1] = __builtin_amdgcn_mfma_f32_16x16x32_bf16(a[mt], b1, acc[mt][nlo + 1], 0, 0, 0);
        }
    };

    {   // diagonal chunks (masked), one per group
        short8 a[2];
        loadA(g1 * 32, a);
        mfma2(a, loadBmask(0, g1 * 32), loadBmask(1, g1 * 32), 0);
        loadA(g2 * 32, a);
        mfma2(a, loadBmask(2, g2 * 32), loadBmask(3, g2 * 32), 2);
    }
    for (int c = g1 + 1; c <= g2; ++c) {   // group-1 only
        short8 a[2];
        loadA(c * 32, a);
        mfma2(a, loadB(0, c * 32), loadB(1, c * 32), 0);
    }
    for (int c = g2 + 1; c < 8; ++c) {     // both groups, shared A-frags
        short8 a[2];
        loadA(c * 32, a);
        mfma2(a, loadB(0, c * 32), loadB(1, c * 32), 0);
        mfma2(a, loadB(2, c * 32), loadB(3, c * 32), 2);
    }

    // --- epilogue: y_part[m] = sum_{i in wave's set} x[m][i]*(T[m][i]+W1[o][i])
    // x read back from LDS (bf16) -- no global round-trip.
    float w1v[4];
#pragma unroll
    for (int nt = 0; nt < 4; ++nt)
        w1v[nt] = W[o * NF + 1 + iRow[nt]];

#pragma unroll
    for (int mt = 0; mt < 2; ++mt) {
#pragma unroll
        for (int r = 0; r < 4; ++r) {
            const int m = mt * 16 + quad * 4 + r;   // C/D: row=quad*4+reg, col=ln
            float p = 0.f;
#pragma unroll
            for (int nt = 0; nt < 4; ++nt) {
                unsigned u = As[m * ASTRIDE + iRow[nt]];
                float xv = __builtin_bit_cast(float, u << 16);
                p = fmaf(xv, acc[mt][nt][r] + w1v[nt], p);
            }
            p += __shfl_xor(p, 1);
            p += __shfl_xor(p, 2);
            p += __shfl_xor(p, 4);
            p += __shfl_xor(p, 8);
            if (ln == 0) red[wave * BM + m] = p;
        }
    }
    __syncthreads();

    if (tid < BM) {
        float s = red[tid] + red[BM + tid] + red[2 * BM + tid] + red[3 * BM + tid]
                + W[o * NF];
        out[(rowbase + tid) * 10 + o] = s;
    }
}

extern "C" void kernel_launch(void* const* d_in, const int* in_sizes, int n_in,
                              void* d_out, int out_size, void* d_ws, size_t ws_size,
                              hipStream_t stream) {
    const float* x = (const float*)d_in[0];   // (4096, 256)
    const float* W = (const float*)d_in[1];   // (10, 33153)
    float* out = (float*)d_out;               // (4096, 10)

    dim3 grid(4096 / BM, 10);
    PolynomialRegression_75385265979710_kernel<<<grid, TPB, 0, stream>>>(x, W, out);
}

// Round 7
// 70.059 us; speedup vs baseline: 1.0699x; 1.0699x over previous
//
#include <hip/hip_runtime.h>

// PolynomialRegression via bf16 MFMA, 2 launches:
//   y[b][o] = bias_o + sum_i x[b][i] * ( (U_o x[b])_i + W1[o][i] )
// gbuild: G (2560x256 bf16) = zero-masked upper-triangular U_o rows.
// main:   64-row x 1-o blocks; x-tile staged fp32->bf16 in LDS (1 barrier);
//         UNIFORM fully-unrolled 9-chunk loop per wave (balanced pairs
//         {w,7-w} -> exactly 72 MFMA/wave, all loads pipelineable);
//         B-frags = raw b128 loads from L2-hot G (no pack, no mask);
//         fused fp32 quadratic-form epilogue, x from LDS, direct stores.

#define DD 256
#define NF 33153
#define TPB 256
#define ASTRIDE 264   // bf16 elems; 528 B row stride -> 2-way LDS alias (free)

typedef __attribute__((ext_vector_type(8))) short short8;
typedef __attribute__((ext_vector_type(4))) float floatx4;
typedef __attribute__((ext_vector_type(4), aligned(4))) float float4a;

union S8U { unsigned u[4]; short8 s; };

__device__ inline unsigned short f2bf(float f) {
    unsigned u = __builtin_bit_cast(unsigned, f);
    return (unsigned short)((u + 0x7FFFu + ((u >> 16) & 1u)) >> 16);  // RNE
}
__device__ inline unsigned pack2(float lo, float hi) {   // 2xfp32 -> bf16x2, half-up
    unsigned a = __builtin_bit_cast(unsigned, hi) + 0x8000u;
    unsigned b = __builtin_bit_cast(unsigned, lo) + 0x8000u;
    return __builtin_amdgcn_perm(a, b, 0x07060302u);
}

// --- prep: scatter W2 into dense upper-triangular G (2560x256 bf16) ---
__global__ __launch_bounds__(TPB)
void gbuild_kernel(const float* __restrict__ W, unsigned short* __restrict__ G) {
    int oi = blockIdx.x;            // o*256 + i
    int o = oi >> 8, i = oi & 255;
    int j = threadIdx.x;
    int base = o * NF + 257 + i * DD - (i * (i - 1)) / 2 - i;   // + j for j>=i
    float v = (j >= i) ? W[base + j] : 0.f;
    G[oi * DD + j] = f2bf(v);
}

// --- main ---
__global__ __launch_bounds__(TPB, 2)
void PolynomialRegression_75385265979710_kernel(const float* __restrict__ x,
                                                const float* __restrict__ W,
                                                const unsigned short* __restrict__ G,
                                                float* __restrict__ out) {
    __shared__ __align__(16) unsigned short As[64 * ASTRIDE];  // 33792 B
    __shared__ float red[4 * 64];

    const int tid  = threadIdx.x;
    const int lane = tid & 63, wave = tid >> 6;
    const int ln   = lane & 15, quad = lane >> 4;
    const int q8   = quad * 8;
    const int rowbase = blockIdx.x * 64;
    const int o  = blockIdx.y;
    const int g1 = wave, g2 = 7 - wave;
    const int rem = 8 - wave;            // chunks in group g1

    // --- stage x-tile (64 x 256) fp32 -> bf16 into padded LDS ---
#pragma unroll
    for (int it = 0; it < 8; ++it) {
        int idx = it * 2048 + tid * 8;
        int r = idx >> 8, c = idx & 255;
        const float* src = &x[(rowbase + r) * DD + c];
        float4a v0 = *(const float4a*)src;
        float4a v1 = *(const float4a*)(src + 4);
        S8U p;
        p.u[0] = pack2(v0.x, v0.y); p.u[1] = pack2(v0.z, v0.w);
        p.u[2] = pack2(v1.x, v1.y); p.u[3] = pack2(v1.z, v1.w);
        *(short8*)&As[r * ASTRIDE + c] = p.s;
    }
    __syncthreads();

    floatx4 acc[4][4];   // [m_tile][n_tile: 0,1 = group g1; 2,3 = group g2]
#pragma unroll
    for (int mt = 0; mt < 4; ++mt)
#pragma unroll
        for (int nt = 0; nt < 4; ++nt) acc[mt][nt] = (floatx4)0.f;

    const unsigned short* Gy = G + (o * DD) * DD;   // G[o] slab (131 KB, L2-hot)

    // --- uniform 9-chunk loop, fully unrolled: t<rem -> (g1, kc=w+t),
    //     else -> (g2, kc=g2+(t-rem)). All bounds compile-time.
#pragma unroll
    for (int t = 0; t < 9; ++t) {
        const bool first = (t < rem);                      // wave-uniform
        const int g  = first ? g1 : g2;
        const int kc = first ? (g1 + t) : (g2 + (t - rem));
        const unsigned short* gb = Gy + (g * 32 + ln) * DD + kc * 32 + q8;
        short8 b0 = *(const short8*)gb;
        short8 b1 = *(const short8*)(gb + 16 * DD);
        short8 a[4];
#pragma unroll
        for (int mt = 0; mt < 4; ++mt)
            a[mt] = *(const short8*)&As[(mt * 16 + ln) * ASTRIDE + kc * 32 + q8];
        if (first) {
#pragma unroll
            for (int mt = 0; mt < 4; ++mt) {
                acc[mt][0] = __builtin_amdgcn_mfma_f32_16x16x32_bf16(a[mt], b0, acc[mt][0], 0, 0, 0);
                acc[mt][1] = __builtin_amdgcn_mfma_f32_16x16x32_bf16(a[mt], b1, acc[mt][1], 0, 0, 0);
            }
        } else {
#pragma unroll
            for (int mt = 0; mt < 4; ++mt) {
                acc[mt][2] = __builtin_amdgcn_mfma_f32_16x16x32_bf16(a[mt], b0, acc[mt][2], 0, 0, 0);
                acc[mt][3] = __builtin_amdgcn_mfma_f32_16x16x32_bf16(a[mt], b1, acc[mt][3], 0, 0, 0);
            }
        }
    }

    // --- epilogue: y_part[m] = sum_{i in wave's set} x[m][i]*(T[m][i]+W1[o][i])
    int iRow[4];
    float w1v[4];
#pragma unroll
    for (int nt = 0; nt < 4; ++nt) {
        int g = (nt < 2) ? g1 : g2;
        iRow[nt] = g * 32 + (nt & 1) * 16 + ln;
        w1v[nt]  = W[o * NF + 1 + iRow[nt]];
    }

#pragma unroll
    for (int mt = 0; mt < 4; ++mt) {
#pragma unroll
        for (int r = 0; r < 4; ++r) {
            const int m = mt * 16 + quad * 4 + r;   // C/D: row=quad*4+reg, col=ln
            float p = 0.f;
#pragma unroll
            for (int nt = 0; nt < 4; ++nt) {
                unsigned u = As[m * ASTRIDE + iRow[nt]];
                float xv = __builtin_bit_cast(float, u << 16);
                p = fmaf(xv, acc[mt][nt][r] + w1v[nt], p);
            }
            p += __shfl_xor(p, 1);
            p += __shfl_xor(p, 2);
            p += __shfl_xor(p, 4);
            p += __shfl_xor(p, 8);
            if (ln == 0) red[wave * 64 + m] = p;
        }
    }
    __syncthreads();

    if (tid < 64) {
        float s = red[tid] + red[64 + tid] + red[128 + tid] + red[192 + tid]
                + W[o * NF];
        out[(rowbase + tid) * 10 + o] = s;
    }
}

extern "C" void kernel_launch(void* const* d_in, const int* in_sizes, int n_in,
                              void* d_out, int out_size, void* d_ws, size_t ws_size,
                              hipStream_t stream) {
    const float* x = (const float*)d_in[0];   // (4096, 256)
    const float* W = (const float*)d_in[1];   // (10, 33153)
    float* out = (float*)d_out;               // (4096, 10)

    unsigned short* G = (unsigned short*)d_ws;   // 1.31 MB

    gbuild_kernel<<<10 * DD, TPB, 0, stream>>>(W, G);

    dim3 grid(4096 / 64, 10);
    PolynomialRegression_75385265979710_kernel<<<grid, TPB, 0, stream>>>(x, W, G, out);
}